// Round 11
// baseline (235.062 us; speedup 1.0000x reference)
//
#include <hip/hip_runtime.h>

// AdaptiveDecayMemory: out = ((Q K^T * scale) ∘ W_decay) V Wo^T * out_scale
// B=4, T=2048, D=1024.  bf16 MFMA, fp32 accum.
// gemmB: 256x256 tile, 4 waves (2x2) of 128x128 (acc 8x8) -> 23.4 B/KFLOP LDS
//   traffic (r9's 45.8 was measured AT the LDS port ceiling; serial model).
//   BK=64, 2x64KB dbuf, r9's proven pipeline + proven (r&7) swizzle.
// gemmP: r9's 128x128 kernel for the fill-limited GEMMs (VT, out).
// R split-K caps spans at 16 K-tiles (f32 partials + radd merge).

using u16 = unsigned short;
typedef __bf16 bf16x8 __attribute__((ext_vector_type(8)));
typedef float f32x4 __attribute__((ext_vector_type(4)));

__device__ inline u16 f2bf(float f) {
  unsigned u = __builtin_bit_cast(unsigned, f);
  unsigned r = (u + 0x7FFFu + ((u >> 16) & 1u)) >> 16;   // RNE
  return (u16)r;
}

__device__ inline void gload16(const u16* g, u16* l) {
  __builtin_amdgcn_global_load_lds(
      (const __attribute__((address_space(1))) void*)g,
      (__attribute__((address_space(3))) void*)l, 16, 0, 0);
}

// ---------- merged prep: x cast + decay GEMV | weight casts ----------
__global__ __launch_bounds__(256) void prep(const float* __restrict__ x,
    u16* __restrict__ Xbf, const float* __restrict__ Wd,
    const float* __restrict__ bd, float* __restrict__ ldec,
    const float* __restrict__ Wq, const float* __restrict__ Wk,
    const float* __restrict__ Wv, const float* __restrict__ Wo,
    u16* __restrict__ Wall) {
  int b = blockIdx.x;
  int t = threadIdx.x;
  if (b < 8192) {
    float4 f = reinterpret_cast<const float4*>(x + (size_t)b * 1024)[t];
    float4 g = reinterpret_cast<const float4*>(Wd)[t];
    ushort4 o;
    o.x = f2bf(f.x); o.y = f2bf(f.y); o.z = f2bf(f.z); o.w = f2bf(f.w);
    reinterpret_cast<ushort4*>(Xbf + (size_t)b * 1024)[t] = o;
    float s = f.x * g.x + f.y * g.y + f.z * g.z + f.w * g.w;
    #pragma unroll
    for (int off = 32; off > 0; off >>= 1) s += __shfl_xor(s, off);
    __shared__ float red[4];
    if ((t & 63) == 0) red[t >> 6] = s;
    __syncthreads();
    if (t == 0) {
      float tot = red[0] + red[1] + red[2] + red[3];
      float dec = 1.f / (1.f + expf(-(tot + bd[0])));
      ldec[b] = logf(dec + 1e-8f);
    }
  } else {
    int wb = b - 8192;
    int m = wb >> 10;
    const float* src = (m == 0) ? Wq : (m == 1) ? Wk : (m == 2) ? Wv : Wo;
    int i = ((wb & 1023) * 256 + t) * 4;
    float4 f = *reinterpret_cast<const float4*>(src + i);
    ushort4 o;
    o.x = f2bf(f.x); o.y = f2bf(f.y); o.z = f2bf(f.z); o.w = f2bf(f.w);
    *reinterpret_cast<ushort4*>(Wall + (size_t)m * 1048576 + i) = o;
  }
}

// ---------- R partial merge: rows 0..1023/batch = bf16(p0+p1) ----------
__global__ __launch_bounds__(256) void radd(const float* __restrict__ p0,
    const float* __restrict__ p1, u16* __restrict__ R) {
  size_t i = ((size_t)blockIdx.x * 256 + threadIdx.x) * 4;
  float4 a = *reinterpret_cast<const float4*>(p0 + i);
  float4 b = *reinterpret_cast<const float4*>(p1 + i);
  size_t batch = i >> 20, within = i & 1048575;
  ushort4 o;
  o.x = f2bf(a.x + b.x); o.y = f2bf(a.y + b.y);
  o.z = f2bf(a.z + b.z); o.w = f2bf(a.w + b.w);
  *reinterpret_cast<ushort4*>(R + batch * 2097152 + within) = o;
}

// ---------- gemmB: 256x256, 4 waves of 128x128, BK=64 ----------
// C[m,n] = sum_k A[m,k]*B[n,k].  MODE 0: bf16.  MODE 1: S tri + decay epi.
// MODE 2: R split-K (it<4 -> f32 partials; it>=4 -> bf16 direct).
template <int MODE>
__global__ __launch_bounds__(256, 1)
void gemmB(const u16* __restrict__ Ab, const u16* __restrict__ Bb,
           void* __restrict__ Cv, int lda, int ldb, int ldc, int K,
           int tiles_n, const float* __restrict__ ldec,
           float* __restrict__ aux0, float* __restrict__ aux1,
           long long abs_, long long bbs_, long long cbs_) {
  __shared__ __align__(16) u16 lds2[65536];   // 2 bufs x (A 32KB | B 32KB) = 128 KiB

  const int batch = blockIdx.y;
  const u16* A = Ab + (size_t)batch * abs_;
  const u16* B = Bb + (size_t)batch * bbs_;

  const int bx = blockIdx.x;
  int it, jt, kt0, kend, ks = 0; bool part = false;
  if (MODE == 0) {
    it = bx / tiles_n; jt = bx % tiles_n; kt0 = 0; kend = K / 64;
  } else if (MODE == 1) {                      // S: 36 tri tiles/batch, jt >= it
    int L = bx; it = 0;
    while (L >= 8 - it) { L -= 8 - it; ++it; }
    jt = it + L; kt0 = 0; kend = 16;
  } else {                                     // R: K=2048 -> 32 K-tiles
    if (bx < 32) {                             // it<4: split-K halves
      it = bx >> 3; int rm = bx & 7; jt = rm >> 1; ks = rm & 1; part = true;
      kt0 = ks ? 16 : 4 * it; kend = ks ? 32 : 16;
    } else {
      int z = bx - 32; it = 4 + (z >> 2); jt = z & 3;
      kt0 = 4 * it; kend = 32;
    }
  }
  const int m0 = it * 256, n0 = jt * 256;

  const int tid = threadIdx.x;
  const int lane = tid & 63;
  const int w = tid >> 6;                      // 0..3
  const int wm = w >> 1, wn = w & 1;           // wave = 128x128
  const int l15 = lane & 15, lhi = lane >> 4;
  const int lr8 = lane >> 3;
  const int schunk = (lane & 7) ^ lr8;         // proven (r&7) involution

  const int span = kend - kt0;

  f32x4 acc[8][8];
  #pragma unroll
  for (int i = 0; i < 8; ++i)
    #pragma unroll
    for (int j = 0; j < 8; ++j) acc[i][j] = (f32x4)0.f;

  // stage one K-tile: A 256x64 (32KB) + B 256x64 (32KB); 16 gloads/thread
  auto stage = [&](int kt, int buf) {
    const size_t kb = (size_t)kt * 64 + schunk * 8;
    u16* la = &lds2[buf * 32768];
    u16* lb = la + 16384;
    #pragma unroll
    for (int u = 0; u < 8; ++u)
      gload16(A + (size_t)(m0 + u * 32 + w * 8 + lr8) * lda + kb,
              la + (u * 32 + w * 8) * 64);
    #pragma unroll
    for (int u = 0; u < 8; ++u)
      gload16(B + (size_t)(n0 + u * 32 + w * 8 + lr8) * ldb + kb,
              lb + (u * 32 + w * 8) * 64);
  };

  stage(kt0, 0);
  asm volatile("s_waitcnt vmcnt(0)" ::: "memory");
  __builtin_amdgcn_s_barrier();

  for (int t = 0; t < span; ++t) {
    const int buf = t & 1;
    if (t + 1 < span) stage(kt0 + t + 1, buf ^ 1);   // issue early, land late

    const u16* baseA = &lds2[buf * 32768];
    const u16* baseB = baseA + 16384;

    bf16x8 bv[8][2];
    #pragma unroll
    for (int ni = 0; ni < 8; ++ni) {
      int r = wn * 128 + ni * 16 + l15;
      #pragma unroll
      for (int kk = 0; kk < 2; ++kk) {
        int s = (kk * 4 + lhi) ^ (r & 7);
        bv[ni][kk] = *reinterpret_cast<const bf16x8*>(&baseB[r * 64 + s * 8]);
      }
    }
    __builtin_amdgcn_s_setprio(1);
    #pragma unroll
    for (int mi = 0; mi < 8; ++mi) {
      int r = wm * 128 + mi * 16 + l15;
      int s0 = lhi ^ (r & 7), s1 = (4 + lhi) ^ (r & 7);
      bf16x8 a0 = *reinterpret_cast<const bf16x8*>(&baseA[r * 64 + s0 * 8]);
      bf16x8 a1 = *reinterpret_cast<const bf16x8*>(&baseA[r * 64 + s1 * 8]);
      #pragma unroll
      for (int ni = 0; ni < 8; ++ni)
        acc[mi][ni] = __builtin_amdgcn_mfma_f32_16x16x32_bf16(a0, bv[ni][0], acc[mi][ni], 0, 0, 0);
      #pragma unroll
      for (int ni = 0; ni < 8; ++ni)
        acc[mi][ni] = __builtin_amdgcn_mfma_f32_16x16x32_bf16(a1, bv[ni][1], acc[mi][ni], 0, 0, 0);
    }
    __builtin_amdgcn_s_setprio(0);

    asm volatile("s_waitcnt vmcnt(0)" ::: "memory");  // t+1 landed (long-body cover)
    __builtin_amdgcn_s_barrier();
  }

  // epilogue: frag (mi,ni) -> row m0+wm*128+mi*16+lhi*4+q, col n0+wn*128+ni*16+l15
  if (MODE == 0) {
    u16* C = (u16*)Cv + (size_t)batch * cbs_;
    #pragma unroll
    for (int mi = 0; mi < 8; ++mi)
      #pragma unroll
      for (int q = 0; q < 4; ++q) {
        int row = m0 + wm * 128 + mi * 16 + lhi * 4 + q;
        u16* crow = C + (size_t)row * ldc + n0 + wn * 128 + l15;
        #pragma unroll
        for (int ni = 0; ni < 8; ++ni) crow[ni * 16] = f2bf(acc[mi][ni][q]);
      }
  } else if (MODE == 1) {
    u16* C = (u16*)Cv + (size_t)batch * cbs_;
    const float* ldp = ldec + (size_t)batch * 2048;
    float ldv[8];
    #pragma unroll
    for (int ni = 0; ni < 8; ++ni) ldv[ni] = ldp[n0 + wn * 128 + ni * 16 + l15];
    const float sc = 0.03125f;   // 1/sqrt(1024)
    #pragma unroll
    for (int mi = 0; mi < 8; ++mi)
      #pragma unroll
      for (int q = 0; q < 4; ++q) {
        int row = m0 + wm * 128 + mi * 16 + lhi * 4 + q;
        u16* crow = C + (size_t)row * ldc + n0 + wn * 128 + l15;
        #pragma unroll
        for (int ni = 0; ni < 8; ++ni) {
          int col = n0 + wn * 128 + ni * 16 + l15;
          int d = col - row;
          float wgt = (d > 0) ? expf(ldv[ni] * (float)(d - 1)) : 0.f;
          crow[ni * 16] = f2bf(acc[mi][ni][q] * sc * wgt);
        }
      }
  } else {
    if (part) {
      float* P = (ks ? aux1 : aux0) + (size_t)batch * 1048576;
      #pragma unroll
      for (int mi = 0; mi < 8; ++mi)
        #pragma unroll
        for (int q = 0; q < 4; ++q) {
          int row = m0 + wm * 128 + mi * 16 + lhi * 4 + q;   // < 1024
          float* crow = P + (size_t)row * 1024 + n0 + wn * 128 + l15;
          #pragma unroll
          for (int ni = 0; ni < 8; ++ni) crow[ni * 16] = acc[mi][ni][q];
        }
    } else {
      u16* C = (u16*)Cv + (size_t)batch * cbs_;
      #pragma unroll
      for (int mi = 0; mi < 8; ++mi)
        #pragma unroll
        for (int q = 0; q < 4; ++q) {
          int row = m0 + wm * 128 + mi * 16 + lhi * 4 + q;
          u16* crow = C + (size_t)row * ldc + n0 + wn * 128 + l15;
          #pragma unroll
          for (int ni = 0; ni < 8; ++ni) crow[ni * 16] = f2bf(acc[mi][ni][q]);
        }
    }
  }
}

// ---------- gemmP: r9's 128x128, BK=64, 2-buf, 2 blocks/CU ----------
// EPI 0: bf16.  EPI 2: f32 * scale.
template <int EPI>
__global__ __launch_bounds__(256, 2)
void gemmP(const u16* __restrict__ Ab, const u16* __restrict__ Bb,
           void* __restrict__ Cv, int lda, int ldb, int ldc, int K,
           int tiles_n, const float* __restrict__ scale_ptr,
           long long abs_, long long bbs_, long long cbs_) {
  __shared__ __align__(16) u16 lds2[32768];   // 2 x (A 16KB | B 16KB)

  const int batch = blockIdx.y;
  const u16* A = Ab + (size_t)batch * abs_;
  const u16* B = Bb + (size_t)batch * bbs_;

  const int it = blockIdx.x / tiles_n;
  const int jt = blockIdx.x % tiles_n;
  const int m0 = it * 128, n0 = jt * 128;

  const int tid = threadIdx.x;
  const int lane = tid & 63;
  const int w = tid >> 6;
  const int wm = (w >> 1) * 64, wn = (w & 1) * 64;
  const int l15 = lane & 15, lhi = lane >> 4;
  const int lr8 = lane >> 3;
  const int schunk = (lane & 7) ^ lr8;

  const int span = K / 64;

  f32x4 acc[4][4];
  #pragma unroll
  for (int i = 0; i < 4; ++i)
    #pragma unroll
    for (int j = 0; j < 4; ++j) acc[i][j] = (f32x4)0.f;

  auto stage = [&](int kt, int buf) {
    const size_t kb = (size_t)kt * 64 + schunk * 8;
    u16* la = &lds2[buf * 16384];
    u16* lb = la + 8192;
    #pragma unroll
    for (int u = 0; u < 4; ++u)
      gload16(A + (size_t)(m0 + u * 32 + w * 8 + lr8) * lda + kb,
              la + (u * 32 + w * 8) * 64);
    #pragma unroll
    for (int u = 0; u < 4; ++u)
      gload16(B + (size_t)(n0 + u * 32 + w * 8 + lr8) * ldb + kb,
              lb + (u * 32 + w * 8) * 64);
  };

  stage(0, 0);
  asm volatile("s_waitcnt vmcnt(0)" ::: "memory");
  __builtin_amdgcn_s_barrier();

  for (int t = 0; t < span; ++t) {
    const int buf = t & 1;
    if (t + 1 < span) stage(t + 1, buf ^ 1);

    const u16* baseA = &lds2[buf * 16384];
    const u16* baseB = baseA + 8192;
    bf16x8 af[4][2], bv[4][2];
    #pragma unroll
    for (int mi = 0; mi < 4; ++mi) {
      int r = wm + mi * 16 + l15;
      #pragma unroll
      for (int kk = 0; kk < 2; ++kk) {
        int s = (kk * 4 + lhi) ^ (r & 7);
        af[mi][kk] = *reinterpret_cast<const bf16x8*>(&baseA[r * 64 + s * 8]);
      }
    }
    #pragma unroll
    for (int ni = 0; ni < 4; ++ni) {
      int r = wn + ni * 16 + l15;
      #pragma unroll
      for (int kk = 0; kk < 2; ++kk) {
        int s = (kk * 4 + lhi) ^ (r & 7);
        bv[ni][kk] = *reinterpret_cast<const bf16x8*>(&baseB[r * 64 + s * 8]);
      }
    }

    __builtin_amdgcn_s_setprio(1);
    #pragma unroll
    for (int kk = 0; kk < 2; ++kk)
      #pragma unroll
      for (int mi = 0; mi < 4; ++mi)
        #pragma unroll
        for (int ni = 0; ni < 4; ++ni)
          acc[mi][ni] = __builtin_amdgcn_mfma_f32_16x16x32_bf16(
              af[mi][kk], bv[ni][kk], acc[mi][ni], 0, 0, 0);
    __builtin_amdgcn_s_setprio(0);

    asm volatile("s_waitcnt vmcnt(0)" ::: "memory");
    __builtin_amdgcn_s_barrier();
  }

  if (EPI == 0) {
    u16* C = (u16*)Cv + (size_t)batch * cbs_;
    #pragma unroll
    for (int mi = 0; mi < 4; ++mi)
      #pragma unroll
      for (int q = 0; q < 4; ++q) {
        int row = m0 + wm + mi * 16 + lhi * 4 + q;
        u16* crow = C + (size_t)row * ldc + n0 + wn + l15;
        #pragma unroll
        for (int ni = 0; ni < 4; ++ni) crow[ni * 16] = f2bf(acc[mi][ni][q]);
      }
  } else {
    float* C = (float*)Cv + (size_t)batch * cbs_;
    const float sc = scale_ptr[0];
    #pragma unroll
    for (int mi = 0; mi < 4; ++mi)
      #pragma unroll
      for (int q = 0; q < 4; ++q) {
        int row = m0 + wm + mi * 16 + lhi * 4 + q;
        float* crow = C + (size_t)row * ldc + n0 + wn + l15;
        #pragma unroll
        for (int ni = 0; ni < 4; ++ni) crow[ni * 16] = acc[mi][ni][q] * sc;
      }
  }
}

extern "C" void kernel_launch(void* const* d_in, const int* in_sizes, int n_in,
                              void* d_out, int out_size, void* d_ws, size_t ws_size,
                              hipStream_t stream) {
  const float* x   = (const float*)d_in[0];
  const float* Wq  = (const float*)d_in[1];
  const float* Wk  = (const float*)d_in[2];
  const float* Wv  = (const float*)d_in[3];
  const float* Wo  = (const float*)d_in[4];
  const float* Wd  = (const float*)d_in[5];
  const float* bd  = (const float*)d_in[6];
  const float* osc = (const float*)d_in[7];
  float* out = (float*)d_out;

  char* ws = (char*)d_ws;
  size_t off = 0;
  u16* Xbf  = (u16*)(ws + off); off += (size_t)8192 * 1024 * 2;
  u16* Wall = (u16*)(ws + off); off += (size_t)4096 * 1024 * 2;
  u16* VT   = (u16*)(ws + off); off += (size_t)1024 * 8192 * 2;
  u16* S    = (u16*)(ws + off); off += (size_t)4 * 2048 * 2048 * 2;
  float* ldec = (float*)(ws + off); off += (size_t)8192 * 4;
  u16* QK   = (u16*)(ws + off); off += (size_t)8192 * 2048 * 2;
  u16* R    = QK;                               // alias: QK dead once S built
  float* Rp0 = (float*)Xbf;                     // alias: Xbf dead after QK+VT
  float* Rp1 = (float*)((char*)QK + 16777216);  // 2nd half of QK region

  u16* Wqk = Wall;
  u16* Wvb = Wall + 2 * 1048576;
  u16* Wob = Wall + 3 * 1048576;

  // 1) merged prep
  prep<<<12288, 256, 0, stream>>>(x, Xbf, Wd, bd, ldec, Wq, Wk, Wv, Wo, Wall);

  // 2) QK = Xbf @ Wqk^T  [8192 x 2048]  (256 blocks, exact fill)
  gemmB<0><<<dim3(32 * 8, 1), 256, 0, stream>>>(
      Xbf, Wqk, QK, 1024, 1024, 2048, 1024, 8, nullptr, nullptr, nullptr,
      0, 0, 0);

  // 3) VT = Wvb @ Xbf^T  [1024 x 8192]  (gemmP, 512 blocks, 2/CU)
  gemmP<0><<<dim3(8 * 64, 1), 256, 0, stream>>>(
      Wvb, Xbf, VT, 1024, 1024, 8192, 1024, 64, nullptr, 0, 0, 0);

  // 4) S_b = (Q_b K_b^T /32) ∘ weights -> bf16, compact tri (36 x 4 blocks)
  gemmB<1><<<dim3(36, 4), 256, 0, stream>>>(
      QK, QK + 1024, S, 2048, 2048, 2048, 1024, 0, ldec, nullptr, nullptr,
      4194304LL, 4194304LL, 4194304LL);

  // 5) R_b = S_b @ V_b, split-K for it<4 (48 x 4 blocks), spans <= 16
  gemmB<2><<<dim3(48, 4), 256, 0, stream>>>(
      S, VT, R, 2048, 8192, 1024, 2048, 0, nullptr, Rp0, Rp1,
      4194304LL, 2048LL, 2097152LL);

  // 5b) merge partials (rows 0..1023 per batch)
  radd<<<4096, 256, 0, stream>>>(Rp0, Rp1, R);

  // 6) out = R @ Wo^T * out_scale  [8192 x 1024] fp32  (gemmP, 512 blocks)
  gemmP<2><<<dim3(64 * 8, 1), 256, 0, stream>>>(
      R, Wob, out, 1024, 1024, 1024, 1024, 8, osc, 0, 0, 0);
}

// Round 12
// 202.448 us; speedup vs baseline: 1.1611x; 1.1611x over previous
//
#include <hip/hip_runtime.h>

// AdaptiveDecayMemory: out = ((Q K^T * scale) ∘ W_decay) V Wo^T * out_scale
// B=4, T=2048, D=1024.  bf16 MFMA, fp32 accum.
// gemmT: 128x128 tile, 2 waves of 128x64 (acc 8x4, ~180 VGPR, no spill),
//   BK=64, SINGLE 32KB LDS buffer, m97/r1 2-barrier loop -> 4 blocks/CU.
//   Read volume halved vs 64x64 waves (24KB vs 64KB per unit); overlap
//   comes from inter-block desync (m114), not intra-block pipelining.
//   Proven (r&7) chunk swizzle both sides.

using u16 = unsigned short;
typedef __bf16 bf16x8 __attribute__((ext_vector_type(8)));
typedef float f32x4 __attribute__((ext_vector_type(4)));

__device__ inline u16 f2bf(float f) {
  unsigned u = __builtin_bit_cast(unsigned, f);
  unsigned r = (u + 0x7FFFu + ((u >> 16) & 1u)) >> 16;   // RNE
  return (u16)r;
}

__device__ inline void gload16(const u16* g, u16* l) {
  __builtin_amdgcn_global_load_lds(
      (const __attribute__((address_space(1))) void*)g,
      (__attribute__((address_space(3))) void*)l, 16, 0, 0);
}

// ---------- merged prep: x cast + decay GEMV | weight casts ----------
__global__ __launch_bounds__(256) void prep(const float* __restrict__ x,
    u16* __restrict__ Xbf, const float* __restrict__ Wd,
    const float* __restrict__ bd, float* __restrict__ ldec,
    const float* __restrict__ Wq, const float* __restrict__ Wk,
    const float* __restrict__ Wv, const float* __restrict__ Wo,
    u16* __restrict__ Wall) {
  int b = blockIdx.x;
  int t = threadIdx.x;
  if (b < 8192) {
    float4 f = reinterpret_cast<const float4*>(x + (size_t)b * 1024)[t];
    float4 g = reinterpret_cast<const float4*>(Wd)[t];
    ushort4 o;
    o.x = f2bf(f.x); o.y = f2bf(f.y); o.z = f2bf(f.z); o.w = f2bf(f.w);
    reinterpret_cast<ushort4*>(Xbf + (size_t)b * 1024)[t] = o;
    float s = f.x * g.x + f.y * g.y + f.z * g.z + f.w * g.w;
    #pragma unroll
    for (int off = 32; off > 0; off >>= 1) s += __shfl_xor(s, off);
    __shared__ float red[4];
    if ((t & 63) == 0) red[t >> 6] = s;
    __syncthreads();
    if (t == 0) {
      float tot = red[0] + red[1] + red[2] + red[3];
      float dec = 1.f / (1.f + expf(-(tot + bd[0])));
      ldec[b] = logf(dec + 1e-8f);
    }
  } else {
    int wb = b - 8192;
    int m = wb >> 10;
    const float* src = (m == 0) ? Wq : (m == 1) ? Wk : (m == 2) ? Wv : Wo;
    int i = ((wb & 1023) * 256 + t) * 4;
    float4 f = *reinterpret_cast<const float4*>(src + i);
    ushort4 o;
    o.x = f2bf(f.x); o.y = f2bf(f.y); o.z = f2bf(f.z); o.w = f2bf(f.w);
    *reinterpret_cast<ushort4*>(Wall + (size_t)m * 1048576 + i) = o;
  }
}

// ---------- gemmT: 128x128, 2 waves of 128x64, BK=64, 1-buf, 4 blocks/CU ----
// C[m,n] = sum_k A[m,k]*B[n,k]  (both K-contiguous).
// MODE 0: bf16.  MODE 1: S compact upper-tri grid + decay epilogue -> bf16.
// MODE 2: f32 * scale_ptr[0].
// diag=1: kt0 = 2*it (R over upper-tri S).  flip=1: batch>=2 reverses it.
template <int MODE>
__global__ __launch_bounds__(128, 2)
void gemmT(const u16* __restrict__ Ab, const u16* __restrict__ Bb,
           void* __restrict__ Cv, int lda, int ldb, int ldc, int K,
           int tiles_n, int diag, int flip, const float* __restrict__ ldec,
           const float* __restrict__ scale_ptr,
           long long abs_, long long bbs_, long long cbs_) {
  __shared__ __align__(16) u16 lds[16384];   // A 128x64 (16KB) | B 128x64 (16KB)

  const int batch = blockIdx.y;
  const u16* A = Ab + (size_t)batch * abs_;
  const u16* B = Bb + (size_t)batch * bbs_;

  int it, jt;
  if (MODE == 1) {                 // compact upper-tri enumeration (136/batch)
    int L = blockIdx.x; it = 0;
    while (L >= 16 - it) { L -= 16 - it; ++it; }
    jt = it + L;
  } else {
    it = blockIdx.x / tiles_n; jt = blockIdx.x % tiles_n;
    if (flip && batch >= 2) it = (gridDim.x / tiles_n - 1) - it;
  }
  const int m0 = it * 128, n0 = jt * 128;

  const int tid = threadIdx.x;
  const int lane = tid & 63;
  const int w = tid >> 6;                      // 0..1
  const int l15 = lane & 15, lhi = lane >> 4;
  const int lr8 = lane >> 3;
  const int schunk = (lane & 7) ^ lr8;         // proven (r&7) involution

  const int kt0 = (MODE != 1 && diag) ? it * 2 : 0;
  const int span = K / 64 - kt0;

  f32x4 acc[8][4];
  #pragma unroll
  for (int i = 0; i < 8; ++i)
    #pragma unroll
    for (int j = 0; j < 4; ++j) acc[i][j] = (f32x4)0.f;

  for (int t = 0; t < span; ++t) {
    __syncthreads();                           // WAR: previous iter's reads done
    const size_t kb = (size_t)(kt0 + t) * 64 + schunk * 8;
    #pragma unroll
    for (int u = 0; u < 8; ++u)                // A: 128 rows x 64 (16 gloads/thr tot)
      gload16(A + (size_t)(m0 + u * 16 + w * 8 + lr8) * lda + kb,
              &lds[(u * 16 + w * 8) * 64]);
    #pragma unroll
    for (int u = 0; u < 8; ++u)                // B: 128 rows x 64
      gload16(B + (size_t)(n0 + u * 16 + w * 8 + lr8) * ldb + kb,
              &lds[8192 + (u * 16 + w * 8) * 64]);
    __syncthreads();                           // full drain: staged data visible

    bf16x8 bv[4][2];
    #pragma unroll
    for (int ni = 0; ni < 4; ++ni) {
      int r = w * 64 + ni * 16 + l15;
      #pragma unroll
      for (int kk = 0; kk < 2; ++kk) {
        int s = (kk * 4 + lhi) ^ (r & 7);
        bv[ni][kk] = *reinterpret_cast<const bf16x8*>(&lds[8192 + r * 64 + s * 8]);
      }
    }
    __builtin_amdgcn_s_setprio(1);
    #pragma unroll
    for (int mi = 0; mi < 8; ++mi) {
      int r = mi * 16 + l15;
      int s0 = lhi ^ (r & 7), s1 = (4 + lhi) ^ (r & 7);
      bf16x8 a0 = *reinterpret_cast<const bf16x8*>(&lds[r * 64 + s0 * 8]);
      bf16x8 a1 = *reinterpret_cast<const bf16x8*>(&lds[r * 64 + s1 * 8]);
      #pragma unroll
      for (int ni = 0; ni < 4; ++ni)
        acc[mi][ni] = __builtin_amdgcn_mfma_f32_16x16x32_bf16(a0, bv[ni][0], acc[mi][ni], 0, 0, 0);
      #pragma unroll
      for (int ni = 0; ni < 4; ++ni)
        acc[mi][ni] = __builtin_amdgcn_mfma_f32_16x16x32_bf16(a1, bv[ni][1], acc[mi][ni], 0, 0, 0);
    }
    __builtin_amdgcn_s_setprio(0);
  }

  // epilogue: frag (mi,ni) -> row m0+mi*16+lhi*4+q, col n0+w*64+ni*16+l15
  if (MODE == 0) {
    u16* C = (u16*)Cv + (size_t)batch * cbs_;
    #pragma unroll
    for (int mi = 0; mi < 8; ++mi)
      #pragma unroll
      for (int q = 0; q < 4; ++q) {
        int row = m0 + mi * 16 + lhi * 4 + q;
        u16* crow = C + (size_t)row * ldc + n0 + w * 64 + l15;
        #pragma unroll
        for (int ni = 0; ni < 4; ++ni) crow[ni * 16] = f2bf(acc[mi][ni][q]);
      }
  } else if (MODE == 1) {
    u16* C = (u16*)Cv + (size_t)batch * cbs_;
    const float* ldp = ldec + (size_t)batch * 2048;
    float ldv[4];
    #pragma unroll
    for (int ni = 0; ni < 4; ++ni) ldv[ni] = ldp[n0 + w * 64 + ni * 16 + l15];
    const float sc = 0.03125f;   // 1/sqrt(1024)
    #pragma unroll
    for (int mi = 0; mi < 8; ++mi)
      #pragma unroll
      for (int q = 0; q < 4; ++q) {
        int row = m0 + mi * 16 + lhi * 4 + q;
        u16* crow = C + (size_t)row * ldc + n0 + w * 64 + l15;
        #pragma unroll
        for (int ni = 0; ni < 4; ++ni) {
          int col = n0 + w * 64 + ni * 16 + l15;
          int d = col - row;
          float wgt = (d > 0) ? expf(ldv[ni] * (float)(d - 1)) : 0.f;
          crow[ni * 16] = f2bf(acc[mi][ni][q] * sc * wgt);
        }
      }
  } else {
    float* C = (float*)Cv + (size_t)batch * cbs_;
    const float sc = scale_ptr[0];
    #pragma unroll
    for (int mi = 0; mi < 8; ++mi)
      #pragma unroll
      for (int q = 0; q < 4; ++q) {
        int row = m0 + mi * 16 + lhi * 4 + q;
        float* crow = C + (size_t)row * ldc + n0 + w * 64 + l15;
        #pragma unroll
        for (int ni = 0; ni < 4; ++ni) crow[ni * 16] = acc[mi][ni][q] * sc;
      }
  }
}

extern "C" void kernel_launch(void* const* d_in, const int* in_sizes, int n_in,
                              void* d_out, int out_size, void* d_ws, size_t ws_size,
                              hipStream_t stream) {
  const float* x   = (const float*)d_in[0];
  const float* Wq  = (const float*)d_in[1];
  const float* Wk  = (const float*)d_in[2];
  const float* Wv  = (const float*)d_in[3];
  const float* Wo  = (const float*)d_in[4];
  const float* Wd  = (const float*)d_in[5];
  const float* bd  = (const float*)d_in[6];
  const float* osc = (const float*)d_in[7];
  float* out = (float*)d_out;

  char* ws = (char*)d_ws;
  size_t off = 0;
  u16* Xbf  = (u16*)(ws + off); off += (size_t)8192 * 1024 * 2;
  u16* Wall = (u16*)(ws + off); off += (size_t)4096 * 1024 * 2;
  u16* VT   = (u16*)(ws + off); off += (size_t)1024 * 8192 * 2;
  u16* S    = (u16*)(ws + off); off += (size_t)4 * 2048 * 2048 * 2;
  float* ldec = (float*)(ws + off); off += (size_t)8192 * 4;
  u16* QK   = (u16*)(ws + off); off += (size_t)8192 * 2048 * 2;
  u16* R    = QK;  // alias: QK dead once S built

  u16* Wqk = Wall;
  u16* Wvb = Wall + 2 * 1048576;
  u16* Wob = Wall + 3 * 1048576;

  // 1) merged prep
  prep<<<12288, 256, 0, stream>>>(x, Xbf, Wd, bd, ldec, Wq, Wk, Wv, Wo, Wall);

  // 2) QK = Xbf @ Wqk^T  [8192 x 2048]  (1024 blocks, 4/CU)
  gemmT<0><<<dim3(64 * 16, 1), 128, 0, stream>>>(
      Xbf, Wqk, QK, 1024, 1024, 2048, 1024, 16, 0, 0, nullptr, nullptr,
      0, 0, 0);

  // 3) VT = Wvb @ Xbf^T  [1024 x 8192]  (512 blocks)
  gemmT<0><<<dim3(8 * 64, 1), 128, 0, stream>>>(
      Wvb, Xbf, VT, 1024, 1024, 8192, 1024, 64, 0, 0, nullptr, nullptr,
      0, 0, 0);

  // 4) S_b = (Q_b K_b^T /32) ∘ weights -> bf16, compact tri (136 x 4 = 544)
  gemmT<1><<<dim3(136, 4), 128, 0, stream>>>(
      QK, QK + 1024, S, 2048, 2048, 2048, 1024, 0, 0, 0, ldec, nullptr,
      4194304LL, 4194304LL, 4194304LL);

  // 5) R_b = S_b @ V_b  [2048 x 1024], kt0=2it, batch-parity flip (512 blocks)
  gemmT<0><<<dim3(16 * 8, 4), 128, 0, stream>>>(
      S, VT, R, 2048, 8192, 1024, 2048, 8, 1, 1, nullptr, nullptr,
      4194304LL, 2048LL, 2097152LL);

  // 6) out = R @ Wo^T * out_scale  [8192 x 1024] fp32  (512 blocks)
  gemmT<2><<<dim3(64 * 8, 1), 128, 0, stream>>>(
      R, Wob, out, 1024, 1024, 1024, 1024, 8, 0, 0, nullptr, osc,
      0, 0, 0);
}

// Round 14
// 172.208 us; speedup vs baseline: 1.3650x; 1.1756x over previous
//
#include <hip/hip_runtime.h>

// AdaptiveDecayMemory: out = ((Q K^T * scale) ∘ W_decay) V Wo^T * out_scale
// B=4, T=2048, D=1024.  bf16 MFMA, fp32 accum.
// r14 = r9 VERBATIM (best validated, 165us) + ONE change: S runs on a compact
// upper-tri grid dim3(136,4) (r12-validated pattern, batch in blockIdx.y)
// instead of the 1024-block grid with early-return dead blocks.
// r13's merged-dispatch + bx-folded decodes are rolled back (post-timing race).

using u16 = unsigned short;
typedef __bf16 bf16x8 __attribute__((ext_vector_type(8)));
typedef float f32x4 __attribute__((ext_vector_type(4)));

__device__ inline u16 f2bf(float f) {
  unsigned u = __builtin_bit_cast(unsigned, f);
  unsigned r = (u + 0x7FFFu + ((u >> 16) & 1u)) >> 16;   // RNE
  return (u16)r;
}

__device__ inline void gload16(const u16* g, u16* l) {
  __builtin_amdgcn_global_load_lds(
      (const __attribute__((address_space(1))) void*)g,
      (__attribute__((address_space(3))) void*)l, 16, 0, 0);
}

// ---------- merged prep: x cast + decay GEMV | weight casts ----------
__global__ __launch_bounds__(256) void prep(const float* __restrict__ x,
    u16* __restrict__ Xbf, const float* __restrict__ Wd,
    const float* __restrict__ bd, float* __restrict__ ldec,
    const float* __restrict__ Wq, const float* __restrict__ Wk,
    const float* __restrict__ Wv, const float* __restrict__ Wo,
    u16* __restrict__ Wall) {
  int b = blockIdx.x;
  int t = threadIdx.x;
  if (b < 8192) {
    float4 f = reinterpret_cast<const float4*>(x + (size_t)b * 1024)[t];
    float4 g = reinterpret_cast<const float4*>(Wd)[t];
    ushort4 o;
    o.x = f2bf(f.x); o.y = f2bf(f.y); o.z = f2bf(f.z); o.w = f2bf(f.w);
    reinterpret_cast<ushort4*>(Xbf + (size_t)b * 1024)[t] = o;
    float s = f.x * g.x + f.y * g.y + f.z * g.z + f.w * g.w;
    #pragma unroll
    for (int off = 32; off > 0; off >>= 1) s += __shfl_xor(s, off);
    __shared__ float red[4];
    if ((t & 63) == 0) red[t >> 6] = s;
    __syncthreads();
    if (t == 0) {
      float tot = red[0] + red[1] + red[2] + red[3];
      float dec = 1.f / (1.f + expf(-(tot + bd[0])));
      ldec[b] = logf(dec + 1e-8f);
    }
  } else {
    int wb = b - 8192;
    int m = wb >> 10;
    const float* src = (m == 0) ? Wq : (m == 1) ? Wk : (m == 2) ? Wv : Wo;
    int i = ((wb & 1023) * 256 + t) * 4;
    float4 f = *reinterpret_cast<const float4*>(src + i);
    ushort4 o;
    o.x = f2bf(f.x); o.y = f2bf(f.y); o.z = f2bf(f.z); o.w = f2bf(f.w);
    *reinterpret_cast<ushort4*>(Wall + (size_t)m * 1048576 + i) = o;
  }
}

// ---------- gemmP: 128x128, BK=64, 2-buf, 2 blocks/CU (r9 body) ----------
// C[m,n] = sum_k A[m,k]*B[n,k]  (both K-contiguous).
// EPI 0: bf16.  EPI 1: S decay epilogue -> bf16 (compact tri grid 136 x 4).
// EPI 2: f32*scale.
// diag=1: kt0 = 2*it (R over upper-tri S).  flip=1: batch>=2 reverses it.
template <int EPI>
__global__ __launch_bounds__(256, 2)
void gemmP(const u16* __restrict__ Ab, const u16* __restrict__ Bb,
           void* __restrict__ Cv, int lda, int ldb, int ldc, int K,
           int tiles_n, int diag, int flip, const float* __restrict__ ldec,
           const float* __restrict__ scale_ptr,
           long long abs_, long long bbs_, long long cbs_) {
  __shared__ __align__(16) u16 lds2[32768];   // 2 x (A 16KB | B 16KB) = 64 KiB

  const int batch = blockIdx.y;
  const u16* A = Ab + (size_t)batch * abs_;
  const u16* B = Bb + (size_t)batch * bbs_;

  int it, jt;
  if (EPI == 1) {                  // compact upper-tri enumeration: 136 tiles
    int L = blockIdx.x;
    it = 0;
    while (L >= 16 - it) { L -= 16 - it; ++it; }
    jt = it + L;
  } else {
    it = blockIdx.x / tiles_n;
    jt = blockIdx.x % tiles_n;
    if (flip && batch >= 2) it = (gridDim.x / tiles_n - 1) - it;
  }
  const int m0 = it * 128, n0 = jt * 128;

  const int tid = threadIdx.x;
  const int lane = tid & 63;
  const int w = tid >> 6;                      // 0..3
  const int wm = (w >> 1) * 64, wn = (w & 1) * 64;   // wave = 64x64
  const int l15 = lane & 15, lhi = lane >> 4;
  const int lr8 = lane >> 3;
  const int schunk = (lane & 7) ^ lr8;         // proven (r&7) involution

  const int kt0 = (EPI != 1 && diag) ? it * 2 : 0;
  const int span = K / 64 - kt0;

  f32x4 acc[4][4];
  #pragma unroll
  for (int i = 0; i < 4; ++i)
    #pragma unroll
    for (int j = 0; j < 4; ++j) acc[i][j] = (f32x4)0.f;

  // stage one K-tile: A 128x64 (16KB) + B 128x64 (16KB); 8 gloads/thread
  auto stage = [&](int kt, int buf) {
    const size_t kb = (size_t)kt * 64 + schunk * 8;
    u16* la = &lds2[buf * 16384];
    u16* lb = la + 8192;
    #pragma unroll
    for (int u = 0; u < 4; ++u)
      gload16(A + (size_t)(m0 + u * 32 + w * 8 + lr8) * lda + kb,
              la + (u * 32 + w * 8) * 64);
    #pragma unroll
    for (int u = 0; u < 4; ++u)
      gload16(B + (size_t)(n0 + u * 32 + w * 8 + lr8) * ldb + kb,
              lb + (u * 32 + w * 8) * 64);
  };

  stage(kt0, 0);
  asm volatile("s_waitcnt vmcnt(0)" ::: "memory");
  __builtin_amdgcn_s_barrier();

  for (int t = 0; t < span; ++t) {
    const int buf = t & 1;
    if (t + 1 < span) stage(kt0 + t + 1, buf ^ 1);   // issue early, land late

    const u16* baseA = &lds2[buf * 16384];
    const u16* baseB = baseA + 8192;
    bf16x8 af[4][2], bv[4][2];
    #pragma unroll
    for (int mi = 0; mi < 4; ++mi) {
      int r = wm + mi * 16 + l15;
      #pragma unroll
      for (int kk = 0; kk < 2; ++kk) {
        int s = (kk * 4 + lhi) ^ (r & 7);
        af[mi][kk] = *reinterpret_cast<const bf16x8*>(&baseA[r * 64 + s * 8]);
      }
    }
    #pragma unroll
    for (int ni = 0; ni < 4; ++ni) {
      int r = wn + ni * 16 + l15;
      #pragma unroll
      for (int kk = 0; kk < 2; ++kk) {
        int s = (kk * 4 + lhi) ^ (r & 7);
        bv[ni][kk] = *reinterpret_cast<const bf16x8*>(&baseB[r * 64 + s * 8]);
      }
    }

    __builtin_amdgcn_s_setprio(1);
    #pragma unroll
    for (int kk = 0; kk < 2; ++kk)
      #pragma unroll
      for (int mi = 0; mi < 4; ++mi)
        #pragma unroll
        for (int ni = 0; ni < 4; ++ni)
          acc[mi][ni] = __builtin_amdgcn_mfma_f32_16x16x32_bf16(
              af[mi][kk], bv[ni][kk], acc[mi][ni], 0, 0, 0);
    __builtin_amdgcn_s_setprio(0);

    asm volatile("s_waitcnt vmcnt(0)" ::: "memory");  // t+1 landed (full iter cover)
    __builtin_amdgcn_s_barrier();
  }

  // epilogue: frag (mi,ni) -> row m0+wm+mi*16+lhi*4+q, col n0+wn+ni*16+l15
  if (EPI == 0) {
    u16* C = (u16*)Cv + (size_t)batch * cbs_;
    #pragma unroll
    for (int mi = 0; mi < 4; ++mi)
      #pragma unroll
      for (int q = 0; q < 4; ++q) {
        int row = m0 + wm + mi * 16 + lhi * 4 + q;
        u16* crow = C + (size_t)row * ldc + n0 + wn + l15;
        #pragma unroll
        for (int ni = 0; ni < 4; ++ni) crow[ni * 16] = f2bf(acc[mi][ni][q]);
      }
  } else if (EPI == 1) {
    u16* C = (u16*)Cv + (size_t)batch * cbs_;
    const float* ldp = ldec + (size_t)batch * 2048;
    float ldv[4];
    #pragma unroll
    for (int ni = 0; ni < 4; ++ni) ldv[ni] = ldp[n0 + wn + ni * 16 + l15];
    const float sc = 0.03125f;   // 1/sqrt(1024)
    #pragma unroll
    for (int mi = 0; mi < 4; ++mi)
      #pragma unroll
      for (int q = 0; q < 4; ++q) {
        int row = m0 + wm + mi * 16 + lhi * 4 + q;
        u16* crow = C + (size_t)row * ldc + n0 + wn + l15;
        #pragma unroll
        for (int ni = 0; ni < 4; ++ni) {
          int col = n0 + wn + ni * 16 + l15;
          int d = col - row;
          float wgt = (d > 0) ? expf(ldv[ni] * (float)(d - 1)) : 0.f;
          crow[ni * 16] = f2bf(acc[mi][ni][q] * sc * wgt);
        }
      }
  } else {
    float* C = (float*)Cv + (size_t)batch * cbs_;
    const float sc = scale_ptr[0];
    #pragma unroll
    for (int mi = 0; mi < 4; ++mi)
      #pragma unroll
      for (int q = 0; q < 4; ++q) {
        int row = m0 + wm + mi * 16 + lhi * 4 + q;
        float* crow = C + (size_t)row * ldc + n0 + wn + l15;
        #pragma unroll
        for (int ni = 0; ni < 4; ++ni) crow[ni * 16] = acc[mi][ni][q] * sc;
      }
  }
}

extern "C" void kernel_launch(void* const* d_in, const int* in_sizes, int n_in,
                              void* d_out, int out_size, void* d_ws, size_t ws_size,
                              hipStream_t stream) {
  const float* x   = (const float*)d_in[0];
  const float* Wq  = (const float*)d_in[1];
  const float* Wk  = (const float*)d_in[2];
  const float* Wv  = (const float*)d_in[3];
  const float* Wo  = (const float*)d_in[4];
  const float* Wd  = (const float*)d_in[5];
  const float* bd  = (const float*)d_in[6];
  const float* osc = (const float*)d_in[7];
  float* out = (float*)d_out;

  char* ws = (char*)d_ws;
  size_t off = 0;
  u16* Xbf  = (u16*)(ws + off); off += (size_t)8192 * 1024 * 2;
  u16* Wall = (u16*)(ws + off); off += (size_t)4096 * 1024 * 2;
  u16* VT   = (u16*)(ws + off); off += (size_t)1024 * 8192 * 2;
  u16* S    = (u16*)(ws + off); off += (size_t)4 * 2048 * 2048 * 2;
  float* ldec = (float*)(ws + off); off += (size_t)8192 * 4;
  u16* QK   = (u16*)(ws + off); off += (size_t)8192 * 2048 * 2;
  u16* R    = QK;  // alias: QK dead once S built

  u16* Wqk = Wall;
  u16* Wvb = Wall + 2 * 1048576;
  u16* Wob = Wall + 3 * 1048576;

  // 1) merged prep: x cast + decay + weight casts
  prep<<<12288, 256, 0, stream>>>(x, Xbf, Wd, bd, ldec, Wq, Wk, Wv, Wo, Wall);

  // 2) QK = Xbf @ Wqk^T  [8192 x 2048]  (1024 blocks, 4/CU)
  gemmP<0><<<dim3(64 * 16, 1), 256, 0, stream>>>(
      Xbf, Wqk, QK, 1024, 1024, 2048, 1024, 16, 0, 0, nullptr, nullptr,
      0, 0, 0);

  // 3) VT = Wvb @ Xbf^T  [1024 x 8192]  (512 blocks, 2/CU)
  gemmP<0><<<dim3(8 * 64, 1), 256, 0, stream>>>(
      Wvb, Xbf, VT, 1024, 1024, 8192, 1024, 64, 0, 0, nullptr, nullptr,
      0, 0, 0);

  // 4) S_b = (Q_b K_b^T /32) ∘ weights -> bf16  (compact tri: 136 x 4 blocks)
  gemmP<1><<<dim3(136, 4), 256, 0, stream>>>(
      QK, QK + 1024, S, 2048, 2048, 2048, 1024, 16, 0, 0, ldec, nullptr,
      4194304LL, 4194304LL, 4194304LL);

  // 5) R_b = S_b @ V_b  [2048 x 1024], kt0=2it, batch-parity flip  (512 blocks)
  gemmP<0><<<dim3(16 * 8, 4), 256, 0, stream>>>(
      S, VT, R, 2048, 8192, 1024, 2048, 8, 1, 1, nullptr, nullptr,
      4194304LL, 2048LL, 2097152LL);

  // 6) out = R @ Wo^T * out_scale  [8192 x 1024] fp32  (512 blocks)
  gemmP<2><<<dim3(64 * 8, 1), 256, 0, stream>>>(
      R, Wob, out, 1024, 1024, 1024, 1024, 8, 0, 0, nullptr, osc,
      0, 0, 0);
}

// Round 15
// 164.965 us; speedup vs baseline: 1.4249x; 1.0439x over previous
//
#include <hip/hip_runtime.h>

// AdaptiveDecayMemory: out = ((Q K^T * scale) ∘ W_decay) V Wo^T * out_scale
// B=4, T=2048, D=1024.  bf16 MFMA, fp32 accum.
// FINAL: r9 configuration verbatim — the session's validated optimum (165us).
// gemmP: 128x128 tile, BK=64, 4 waves (wave 64x64), 2x32KB LDS dbuf,
//   2 blocks/CU, stage(t+1)-at-top / vmcnt(0)+barrier-at-bottom pipeline,
//   conflict-free (r&7) chunk swizzle (both-sides involution, rule #21).
// Upper-tri structure exploited: S skips dead tiles (early return), R starts
// its K-loop at the diagonal (kt0=2it) with batch-parity balancing.
// Plateau note: all dispatches run ~1690 cyc per 128²xBK64 unit (~765 TF),
// the m97-structure ceiling at these shapes; the m201 8-phase rung was
// attempted 6x (r2,r3,r5-r8) and never reproduced — see session journal.

using u16 = unsigned short;
typedef __bf16 bf16x8 __attribute__((ext_vector_type(8)));
typedef float f32x4 __attribute__((ext_vector_type(4)));

__device__ inline u16 f2bf(float f) {
  unsigned u = __builtin_bit_cast(unsigned, f);
  unsigned r = (u + 0x7FFFu + ((u >> 16) & 1u)) >> 16;   // RNE
  return (u16)r;
}

__device__ inline void gload16(const u16* g, u16* l) {
  __builtin_amdgcn_global_load_lds(
      (const __attribute__((address_space(1))) void*)g,
      (__attribute__((address_space(3))) void*)l, 16, 0, 0);
}

// ---------- merged prep: x cast + decay GEMV | weight casts ----------
__global__ __launch_bounds__(256) void prep(const float* __restrict__ x,
    u16* __restrict__ Xbf, const float* __restrict__ Wd,
    const float* __restrict__ bd, float* __restrict__ ldec,
    const float* __restrict__ Wq, const float* __restrict__ Wk,
    const float* __restrict__ Wv, const float* __restrict__ Wo,
    u16* __restrict__ Wall) {
  int b = blockIdx.x;
  int t = threadIdx.x;
  if (b < 8192) {
    float4 f = reinterpret_cast<const float4*>(x + (size_t)b * 1024)[t];
    float4 g = reinterpret_cast<const float4*>(Wd)[t];
    ushort4 o;
    o.x = f2bf(f.x); o.y = f2bf(f.y); o.z = f2bf(f.z); o.w = f2bf(f.w);
    reinterpret_cast<ushort4*>(Xbf + (size_t)b * 1024)[t] = o;
    float s = f.x * g.x + f.y * g.y + f.z * g.z + f.w * g.w;
    #pragma unroll
    for (int off = 32; off > 0; off >>= 1) s += __shfl_xor(s, off);
    __shared__ float red[4];
    if ((t & 63) == 0) red[t >> 6] = s;
    __syncthreads();
    if (t == 0) {
      float tot = red[0] + red[1] + red[2] + red[3];
      float dec = 1.f / (1.f + expf(-(tot + bd[0])));
      ldec[b] = logf(dec + 1e-8f);
    }
  } else {
    int wb = b - 8192;
    int m = wb >> 10;
    const float* src = (m == 0) ? Wq : (m == 1) ? Wk : (m == 2) ? Wv : Wo;
    int i = ((wb & 1023) * 256 + t) * 4;
    float4 f = *reinterpret_cast<const float4*>(src + i);
    ushort4 o;
    o.x = f2bf(f.x); o.y = f2bf(f.y); o.z = f2bf(f.z); o.w = f2bf(f.w);
    *reinterpret_cast<ushort4*>(Wall + (size_t)m * 1048576 + i) = o;
  }
}

// ---------- gemmP: 128x128, BK=64, 2-buf, 2 blocks/CU ----------
// C[m,n] = sum_k A[m,k]*B[n,k]  (both K-contiguous).
// EPI 0: bf16.  EPI 1: S decay epilogue -> bf16 (skip jt<it).  EPI 2: f32*scale.
// diag=1: kt0 = 2*it (R over upper-tri S).  flip=1: batch>=2 reverses it.
template <int EPI>
__global__ __launch_bounds__(256, 2)
void gemmP(const u16* __restrict__ Ab, const u16* __restrict__ Bb,
           void* __restrict__ Cv, int lda, int ldb, int ldc, int K,
           int tiles_n, int diag, int flip, const float* __restrict__ ldec,
           const float* __restrict__ scale_ptr,
           long long abs_, long long bbs_, long long cbs_) {
  __shared__ __align__(16) u16 lds2[32768];   // 2 x (A 16KB | B 16KB) = 64 KiB

  const int batch = blockIdx.y;
  const u16* A = Ab + (size_t)batch * abs_;
  const u16* B = Bb + (size_t)batch * bbs_;

  int it = blockIdx.x / tiles_n;
  const int jt = blockIdx.x % tiles_n;
  if (flip && batch >= 2) it = (gridDim.x / tiles_n - 1) - it;
  if (EPI == 1 && jt < it) return;   // strictly-lower S tiles are zero, never read
  const int m0 = it * 128, n0 = jt * 128;

  const int tid = threadIdx.x;
  const int lane = tid & 63;
  const int w = tid >> 6;                      // 0..3
  const int wm = (w >> 1) * 64, wn = (w & 1) * 64;   // wave = 64x64
  const int l15 = lane & 15, lhi = lane >> 4;
  const int lr8 = lane >> 3;
  const int schunk = (lane & 7) ^ lr8;         // pre-swizzled source chunk

  const int kt0 = diag ? it * 2 : 0;
  const int nkt = K / 64;
  const int span = nkt - kt0;

  f32x4 acc[4][4];
  #pragma unroll
  for (int i = 0; i < 4; ++i)
    #pragma unroll
    for (int j = 0; j < 4; ++j) acc[i][j] = (f32x4)0.f;

  // stage one K-tile: A 128x64 (16KB) + B 128x64 (16KB); 8 gloads/thread
  auto stage = [&](int kt, int buf) {
    const size_t kb = (size_t)kt * 64 + schunk * 8;
    u16* la = &lds2[buf * 16384];
    u16* lb = la + 8192;
    #pragma unroll
    for (int u = 0; u < 4; ++u)
      gload16(A + (size_t)(m0 + u * 32 + w * 8 + lr8) * lda + kb,
              la + (u * 32 + w * 8) * 64);
    #pragma unroll
    for (int u = 0; u < 4; ++u)
      gload16(B + (size_t)(n0 + u * 32 + w * 8 + lr8) * ldb + kb,
              lb + (u * 32 + w * 8) * 64);
  };

  stage(kt0, 0);
  asm volatile("s_waitcnt vmcnt(0)" ::: "memory");
  __builtin_amdgcn_s_barrier();

  for (int t = 0; t < span; ++t) {
    const int buf = t & 1;
    if (t + 1 < span) stage(kt0 + t + 1, buf ^ 1);   // issue early, land late

    const u16* baseA = &lds2[buf * 16384];
    const u16* baseB = baseA + 8192;
    bf16x8 af[4][2], bv[4][2];
    #pragma unroll
    for (int mi = 0; mi < 4; ++mi) {
      int r = wm + mi * 16 + l15;
      #pragma unroll
      for (int kk = 0; kk < 2; ++kk) {
        int s = (kk * 4 + lhi) ^ (r & 7);
        af[mi][kk] = *reinterpret_cast<const bf16x8*>(&baseA[r * 64 + s * 8]);
      }
    }
    #pragma unroll
    for (int ni = 0; ni < 4; ++ni) {
      int r = wn + ni * 16 + l15;
      #pragma unroll
      for (int kk = 0; kk < 2; ++kk) {
        int s = (kk * 4 + lhi) ^ (r & 7);
        bv[ni][kk] = *reinterpret_cast<const bf16x8*>(&baseB[r * 64 + s * 8]);
      }
    }

    __builtin_amdgcn_s_setprio(1);
    #pragma unroll
    for (int kk = 0; kk < 2; ++kk)
      #pragma unroll
      for (int mi = 0; mi < 4; ++mi)
        #pragma unroll
        for (int ni = 0; ni < 4; ++ni)
          acc[mi][ni] = __builtin_amdgcn_mfma_f32_16x16x32_bf16(
              af[mi][kk], bv[ni][kk], acc[mi][ni], 0, 0, 0);
    __builtin_amdgcn_s_setprio(0);

    asm volatile("s_waitcnt vmcnt(0)" ::: "memory");  // t+1 landed (full iter cover)
    __builtin_amdgcn_s_barrier();
  }

  // epilogue: frag (mi,ni) -> row m0+wm+mi*16+lhi*4+q, col n0+wn+ni*16+l15
  if (EPI == 0) {
    u16* C = (u16*)Cv + (size_t)batch * cbs_;
    #pragma unroll
    for (int mi = 0; mi < 4; ++mi)
      #pragma unroll
      for (int q = 0; q < 4; ++q) {
        int row = m0 + wm + mi * 16 + lhi * 4 + q;
        u16* crow = C + (size_t)row * ldc + n0 + wn + l15;
        #pragma unroll
        for (int ni = 0; ni < 4; ++ni) crow[ni * 16] = f2bf(acc[mi][ni][q]);
      }
  } else if (EPI == 1) {
    u16* C = (u16*)Cv + (size_t)batch * cbs_;
    const float* ldp = ldec + (size_t)batch * 2048;
    float ldv[4];
    #pragma unroll
    for (int ni = 0; ni < 4; ++ni) ldv[ni] = ldp[n0 + wn + ni * 16 + l15];
    const float sc = 0.03125f;   // 1/sqrt(1024)
    #pragma unroll
    for (int mi = 0; mi < 4; ++mi)
      #pragma unroll
      for (int q = 0; q < 4; ++q) {
        int row = m0 + wm + mi * 16 + lhi * 4 + q;
        u16* crow = C + (size_t)row * ldc + n0 + wn + l15;
        #pragma unroll
        for (int ni = 0; ni < 4; ++ni) {
          int col = n0 + wn + ni * 16 + l15;
          int d = col - row;
          float wgt = (d > 0) ? expf(ldv[ni] * (float)(d - 1)) : 0.f;
          crow[ni * 16] = f2bf(acc[mi][ni][q] * sc * wgt);
        }
      }
  } else {
    float* C = (float*)Cv + (size_t)batch * cbs_;
    const float sc = scale_ptr[0];
    #pragma unroll
    for (int mi = 0; mi < 4; ++mi)
      #pragma unroll
      for (int q = 0; q < 4; ++q) {
        int row = m0 + wm + mi * 16 + lhi * 4 + q;
        float* crow = C + (size_t)row * ldc + n0 + wn + l15;
        #pragma unroll
        for (int ni = 0; ni < 4; ++ni) crow[ni * 16] = acc[mi][ni][q] * sc;
      }
  }
}

extern "C" void kernel_launch(void* const* d_in, const int* in_sizes, int n_in,
                              void* d_out, int out_size, void* d_ws, size_t ws_size,
                              hipStream_t stream) {
  const float* x   = (const float*)d_in[0];
  const float* Wq  = (const float*)d_in[1];
  const float* Wk  = (const float*)d_in[2];
  const float* Wv  = (const float*)d_in[3];
  const float* Wo  = (const float*)d_in[4];
  const float* Wd  = (const float*)d_in[5];
  const float* bd  = (const float*)d_in[6];
  const float* osc = (const float*)d_in[7];
  float* out = (float*)d_out;

  char* ws = (char*)d_ws;
  size_t off = 0;
  u16* Xbf  = (u16*)(ws + off); off += (size_t)8192 * 1024 * 2;
  u16* Wall = (u16*)(ws + off); off += (size_t)4096 * 1024 * 2;
  u16* VT   = (u16*)(ws + off); off += (size_t)1024 * 8192 * 2;
  u16* S    = (u16*)(ws + off); off += (size_t)4 * 2048 * 2048 * 2;
  float* ldec = (float*)(ws + off); off += (size_t)8192 * 4;
  u16* QK   = (u16*)(ws + off); off += (size_t)8192 * 2048 * 2;
  u16* R    = QK;  // alias: QK dead once S built

  u16* Wqk = Wall;
  u16* Wvb = Wall + 2 * 1048576;
  u16* Wob = Wall + 3 * 1048576;

  // 1) merged prep: x cast + decay + weight casts
  prep<<<12288, 256, 0, stream>>>(x, Xbf, Wd, bd, ldec, Wq, Wk, Wv, Wo, Wall);

  // 2) QK = Xbf @ Wqk^T  [8192 x 2048]  (1024 blocks, 4/CU)
  gemmP<0><<<dim3(64 * 16, 1), 256, 0, stream>>>(
      Xbf, Wqk, QK, 1024, 1024, 2048, 1024, 16, 0, 0, nullptr, nullptr,
      0, 0, 0);

  // 3) VT = Wvb @ Xbf^T  [1024 x 8192]  (512 blocks, 2/CU)
  gemmP<0><<<dim3(8 * 64, 1), 256, 0, stream>>>(
      Wvb, Xbf, VT, 1024, 1024, 8192, 1024, 64, 0, 0, nullptr, nullptr,
      0, 0, 0);

  // 4) S_b = (Q_b K_b^T /32) ∘ weights -> bf16  (544 live of 1024)
  gemmP<1><<<dim3(16 * 16, 4), 256, 0, stream>>>(
      QK, QK + 1024, S, 2048, 2048, 2048, 1024, 16, 0, 0, ldec, nullptr,
      4194304LL, 4194304LL, 4194304LL);

  // 5) R_b = S_b @ V_b  [2048 x 1024], kt0=2it, batch-parity flip  (512 blocks)
  gemmP<0><<<dim3(16 * 8, 4), 256, 0, stream>>>(
      S, VT, R, 2048, 8192, 1024, 2048, 8, 1, 1, nullptr, nullptr,
      4194304LL, 2048LL, 2097152LL);

  // 6) out = R @ Wo^T * out_scale  [8192 x 1024] fp32  (512 blocks)
  gemmP<2><<<dim3(64 * 8, 1), 256, 0, stream>>>(
      R, Wob, out, 1024, 1024, 1024, 1024, 8, 0, 0, nullptr, osc,
      0, 0, 0);
}